// Round 6
// baseline (132.612 us; speedup 1.0000x reference)
//
#include <hip/hip_runtime.h>
#include <math.h>
#include <stdint.h>

#define VOCAB 100000
#define DIM   128
#define BATCH 16384
#define CMAX  10
#define KNEG  5

typedef float f32x4 __attribute__((ext_vector_type(4)));

// Numerically stable log(sigmoid(x)) = min(x,0) - log1p(exp(-|x|))
__device__ __forceinline__ float log_sigmoid(float x) {
    return fminf(x, 0.0f) - log1pf(expf(-fabsf(x)));
}

// DPP-based 32-lane sum: after 5 dependent VALU adds, lane 31 holds
// sum(lanes 0..31) and lane 63 holds sum(lanes 32..63).
#define DPP_ADD_STEP(v, ctrl)                                                  \
    v += __int_as_float(__builtin_amdgcn_update_dpp(                           \
        0, __float_as_int(v), (ctrl), 0xF, 0xF, false))

__device__ __forceinline__ float dpp_reduce32_to_lane31(float v) {
    DPP_ADD_STEP(v, 0x111);  // row_shr:1
    DPP_ADD_STEP(v, 0x112);  // row_shr:2
    DPP_ADD_STEP(v, 0x114);  // row_shr:4
    DPP_ADD_STEP(v, 0x118);  // row_shr:8
    DPP_ADD_STEP(v, 0x142);  // row_bcast:15
    return v;
}

// ---------------------------------------------------------------------------
// R6: L3 re-warm. R1/R4 (per-wave MLP) and R5 (request count -35%) were all
// null -> the gather is bound downstream by outstanding_misses/XCD divided by
// miss LATENCY (~900 cy HBM-cold, because the harness's 256 MiB poison fill
// wipes L3 every iteration). Latency is the one unfalsified factor: stream
// out_emb (51.2 MB, 80% of unique miss bytes) through L3 first at streaming
// BW (~6 TB/s, immune to the random-gather cap), turning gather misses into
// ~300-400 cy L3 hits. Discriminating experiment: if flat, the path is
// request-RATE bound and we are at the structural roofline.
// ---------------------------------------------------------------------------
__global__ __launch_bounds__(256) void prefetch_kernel(
    const float* __restrict__ p, int n4)
{
    const f32x4* v = (const f32x4*)p;
    int i = blockIdx.x * 256 + threadIdx.x;
    const int stride = gridDim.x * 256;
    float ax = 0.0f, ay = 0.0f, az = 0.0f, aw = 0.0f;
    for (; i < n4; i += stride) {
        f32x4 x = v[i];
        ax += x.x; ay += x.y; az += x.z; aw += x.w;
    }
    // rule #17: keep the loads live without a store
    asm volatile("" :: "v"(ax), "v"(ay), "v"(az), "v"(aw));
}

// ---------------------------------------------------------------------------
// Score+loss: R5 structure unchanged (lowest request count: if the latency
// drops, the rate cap rises and fewer requests start to matter). One wave
// per sample; switch(len) -> straight-line template body issuing exactly
// 1 + ceil((len+5)/2) full-wave dwordx4 gathers (half 0 even rows, half 1
// odd rows of packed [ctx[0..len-1], neg[0..4]]).
// ---------------------------------------------------------------------------
template<int LEN>
__device__ __forceinline__ void body(
    int t_word, const int (&ctxw)[CMAX], const int (&negw)[KNEG],
    const float* __restrict__ in_emb, const float* __restrict__ out_emb,
    int sub, int half, uint32_t sub16, float2& res)
{
    constexpr int ROWS  = LEN + KNEG;          // valid rows (6..15)
    constexpr int SLOTS = (ROWS + 1) & ~1;     // padded even (6..16)
    constexpr int NI    = SLOTS / 2;           // row-load instrs (3..8)

    int wr[SLOTS];
#pragma unroll
    for (int r = 0; r < SLOTS; ++r) {
        const int ci  = (r < CMAX) ? r : 0;                  // safe ctx idx
        int       ni  = (r >= LEN) ? (r - LEN) : 0;          // safe neg idx
        ni = (ni > KNEG - 1) ? (KNEG - 1) : ni;              // pad -> negw[4]
        wr[r] = (r < LEN) ? ctxw[ci] : negw[ni];
    }

    int w[NI];
#pragma unroll
    for (int jj = 0; jj < NI; ++jj)
        w[jj] = half ? wr[2 * jj + 1] : wr[2 * jj];

    // ---- issue t + NI row gathers back-to-back, one vmcnt(0) ----
    f32x4 tv;
    asm volatile("global_load_dwordx4 %0, %1, %2"
                 : "=v"(tv)
                 : "v"((uint32_t)t_word * 512u + sub16), "s"(in_emb));
    f32x4 rv[NI];
#pragma unroll
    for (int jj = 0; jj < NI; ++jj) {
        asm volatile("global_load_dwordx4 %0, %1, %2"
                     : "=v"(rv[jj])
                     : "v"((uint32_t)w[jj] * 512u + sub16), "s"(out_emb));
    }
    asm volatile("s_waitcnt vmcnt(0)" ::: "memory");
    __builtin_amdgcn_sched_barrier(0);        // rule #18: pin consumers below

    // ---- dots + per-half DPP reduce ----
    float bc[8];
#pragma unroll
    for (int jj = 0; jj < 8; ++jj) bc[jj] = 0.0f;
#pragma unroll
    for (int jj = 0; jj < NI; ++jj) {
        float d = tv.x * rv[jj].x + tv.y * rv[jj].y +
                  tv.z * rv[jj].z + tv.w * rv[jj].w;
        float p = dpp_reduce32_to_lane31(d);
        bc[jj] = __shfl(p, 31, 32);
    }

    // ---- 8-way mux: lane (half, sel) owns row r = 2*sel + half ----
    const int sel = sub & 7;
    float a0 = (sel & 1) ? bc[1] : bc[0];
    float a1 = (sel & 1) ? bc[3] : bc[2];
    float a2 = (sel & 1) ? bc[5] : bc[4];
    float a3 = (sel & 1) ? bc[7] : bc[6];
    float b0 = (sel & 2) ? a1 : a0;
    float b1 = (sel & 2) ? a3 : a2;
    float sv = (sel & 4) ? b1 : b0;

    const int  r      = 2 * sel + half;
    const bool is_neg = (r >= LEN);
    const bool active = (sub < 8) && (r < ROWS);

    float v    = log_sigmoid(is_neg ? -sv : sv);
    float posc = (active && !is_neg) ? v : 0.0f;
    float negc = (active &&  is_neg) ? v : 0.0f;

    posc += __shfl_xor(posc, 1, 64);
    posc += __shfl_xor(posc, 2, 64);
    posc += __shfl_xor(posc, 4, 64);
    posc += __shfl_xor(posc, 32, 64);
    negc += __shfl_xor(negc, 1, 64);
    negc += __shfl_xor(negc, 2, 64);
    negc += __shfl_xor(negc, 4, 64);
    negc += __shfl_xor(negc, 32, 64);

    res.x = -posc * (1.0f / (float)LEN);
    res.y = -negc * (1.0f / KNEG);
}

__global__ __launch_bounds__(256) void score_loss_kernel(
    const int*   __restrict__ tgt,
    const int*   __restrict__ ctx,
    const int*   __restrict__ lens,
    const int*   __restrict__ neg,
    const float* __restrict__ in_emb,
    const float* __restrict__ out_emb,
    float2*      __restrict__ per_sample,  // ws: [BATCH]
    float*       __restrict__ out)
{
    const int tid  = threadIdx.x;
    const int lane = tid & 63;
    const int sub  = lane & 31;              // lane within half-wave
    const int half = lane >> 5;
    const int b    = (blockIdx.x * 256 + tid) >> 6;   // one wave per sample
    const int bu   = __builtin_amdgcn_readfirstlane(b);

    if (blockIdx.x == 0 && tid < 2) out[tid] = 0.0f;

    // ---- scalar index loads (uniform address -> s_load, lgkm domain) ----
    const int len    = lens[bu];
    const int t_word = tgt[bu];
    int ctxw[CMAX];
#pragma unroll
    for (int c = 0; c < CMAX; ++c) ctxw[c] = ctx[bu * CMAX + c];
    int negw[KNEG];
#pragma unroll
    for (int k = 0; k < KNEG; ++k) negw[k] = neg[bu * KNEG + k];

    const uint32_t sub16 = (uint32_t)sub * 16u;
    float2 res; res.x = 0.0f; res.y = 0.0f;

    // wave-uniform switch: scalar branch, no exec divergence
    switch (len) {
    case 1:  body<1> (t_word, ctxw, negw, in_emb, out_emb, sub, half, sub16, res); break;
    case 2:  body<2> (t_word, ctxw, negw, in_emb, out_emb, sub, half, sub16, res); break;
    case 3:  body<3> (t_word, ctxw, negw, in_emb, out_emb, sub, half, sub16, res); break;
    case 4:  body<4> (t_word, ctxw, negw, in_emb, out_emb, sub, half, sub16, res); break;
    case 5:  body<5> (t_word, ctxw, negw, in_emb, out_emb, sub, half, sub16, res); break;
    case 6:  body<6> (t_word, ctxw, negw, in_emb, out_emb, sub, half, sub16, res); break;
    case 7:  body<7> (t_word, ctxw, negw, in_emb, out_emb, sub, half, sub16, res); break;
    case 8:  body<8> (t_word, ctxw, negw, in_emb, out_emb, sub, half, sub16, res); break;
    case 9:  body<9> (t_word, ctxw, negw, in_emb, out_emb, sub, half, sub16, res); break;
    case 10: body<10>(t_word, ctxw, negw, in_emb, out_emb, sub, half, sub16, res); break;
    default: break;                          // len == 0: res stays (0,0)
    }

    if (lane == 0) per_sample[b] = res;
}

// ---------------------------------------------------------------------------
// Kernel B: one thread per sample, reads 128 KB of float2 from L2.
// ---------------------------------------------------------------------------
__global__ __launch_bounds__(256) void reduce_kernel(
    const float2* __restrict__ per_sample,
    float*        __restrict__ out)
{
    const int tid = threadIdx.x;
    const int b   = blockIdx.x * 256 + tid;   // 64 blocks cover BATCH exactly

    const float2 pr = per_sample[b];
    float pos = pr.x;
    float neg = pr.y;

#pragma unroll
    for (int m = 32; m >= 1; m >>= 1) {
        pos += __shfl_xor(pos, m, 64);
        neg += __shfl_xor(neg, m, 64);
    }
    __shared__ float s_pos[4];
    __shared__ float s_neg[4];
    const int wave = tid >> 6;
    if ((tid & 63) == 0) { s_pos[wave] = pos; s_neg[wave] = neg; }
    __syncthreads();
    if (tid == 0) {
        float ps = s_pos[0] + s_pos[1] + s_pos[2] + s_pos[3];
        float ns = s_neg[0] + s_neg[1] + s_neg[2] + s_neg[3];
        atomicAdd(&out[0], ps * (1.0f / BATCH));
        atomicAdd(&out[1], ns * (1.0f / BATCH));
    }
}

extern "C" void kernel_launch(void* const* d_in, const int* in_sizes, int n_in,
                              void* d_out, int out_size, void* d_ws, size_t ws_size,
                              hipStream_t stream) {
    const int*   tgt     = (const int*)  d_in[0];
    const int*   ctx     = (const int*)  d_in[1];
    const int*   lens    = (const int*)  d_in[2];
    const int*   neg     = (const int*)  d_in[3];
    const float* in_emb  = (const float*)d_in[4];
    const float* out_emb = (const float*)d_in[5];
    float* out          = (float*)d_out;
    float2* per_sample  = (float2*)d_ws;      // BATCH * 8 B = 128 KiB scratch

    // Warm L3 with out_emb (51.2 MB streaming; 80% of unique miss bytes).
    prefetch_kernel<<<2048, 256, 0, stream>>>(out_emb, VOCAB * DIM / 4);

    // one 64-lane wave per sample; 4 samples per 256-thread block
    score_loss_kernel<<<BATCH / 4, 256, 0, stream>>>(
        tgt, ctx, lens, neg, in_emb, out_emb, per_sample, out);

    reduce_kernel<<<BATCH / 256, 256, 0, stream>>>(per_sample, out);
}

// Round 7
// 127.488 us; speedup vs baseline: 1.0402x; 1.0402x over previous
//
#include <hip/hip_runtime.h>
#include <math.h>
#include <stdint.h>

#define VOCAB 100000
#define DIM   128
#define BATCH 16384
#define CMAX  10
#define KNEG  5

typedef float f32x4 __attribute__((ext_vector_type(4)));

// Numerically stable log(sigmoid(x)) = min(x,0) - log1p(exp(-|x|))
__device__ __forceinline__ float log_sigmoid(float x) {
    return fminf(x, 0.0f) - log1pf(expf(-fabsf(x)));
}

// DPP-based 32-lane sum: after 5 dependent VALU adds, lane 31 holds
// sum(lanes 0..31) and lane 63 holds sum(lanes 32..63).
#define DPP_ADD_STEP(v, ctrl)                                                  \
    v += __int_as_float(__builtin_amdgcn_update_dpp(                           \
        0, __float_as_int(v), (ctrl), 0xF, 0xF, false))

__device__ __forceinline__ float dpp_reduce32_to_lane31(float v) {
    DPP_ADD_STEP(v, 0x111);  // row_shr:1
    DPP_ADD_STEP(v, 0x112);  // row_shr:2
    DPP_ADD_STEP(v, 0x114);  // row_shr:4
    DPP_ADD_STEP(v, 0x118);  // row_shr:8
    DPP_ADD_STEP(v, 0x142);  // row_bcast:15
    return v;
}

// ---------------------------------------------------------------------------
// FINAL (R3 structure, best measured 126.9 us). ONE WAVE per sample,
// half-wave h owns scores j = h*8 .. h*8+7 (j=15 dummy). 9 dwordx4 gathers
// per half-wave issued back-to-back, staged vmcnt waits, fused loss.
//  (a) index loads scalarized via readfirstlane -> s_load (SMEM/lgkmcnt):
//      fewer ops, fewer VGPRs, and vmcnt counts exactly our 9 asm gathers.
//  (b) masked ctx slots (j >= len) and the dummy slot redirect their word to
//      negw[0]: duplicate addresses MSHR/L1-merge with the in-flight neg row.
// Ceiling evidence (R1/R4/R5/R6): the gather is bound by the random-128B
// line service rate of the L2/fabric path (~1.1 TB/s effective) on the
// ~42 MB unique working set; per-wave MLP x2 (null), request count -35%
// (null), and L3 pre-warm (cost only) all failed to move it.
// ---------------------------------------------------------------------------
__global__ __launch_bounds__(256) void score_loss_kernel(
    const int*   __restrict__ tgt,
    const int*   __restrict__ ctx,
    const int*   __restrict__ lens,
    const int*   __restrict__ neg,
    const float* __restrict__ in_emb,
    const float* __restrict__ out_emb,
    float2*      __restrict__ per_sample,  // ws: [BATCH]
    float*       __restrict__ out)
{
    const int tid  = threadIdx.x;
    const int lane = tid & 63;
    const int sub  = lane & 31;              // lane within half-wave
    const int half = lane >> 5;              // which 8-score group
    const int b    = (blockIdx.x * 256 + tid) >> 6;   // one wave per sample
    const int bu   = __builtin_amdgcn_readfirstlane(b);

    if (blockIdx.x == 0 && tid < 2) out[tid] = 0.0f;

    // ---- scalar index loads (uniform address -> s_load, lgkmcnt domain) ----
    const int len    = lens[bu];
    const int t_word = tgt[bu];
    int ctxw[CMAX];
#pragma unroll
    for (int c = 0; c < CMAX; ++c) ctxw[c] = ctx[bu * CMAX + c];
    int negw[KNEG];
#pragma unroll
    for (int k = 0; k < KNEG; ++k) negw[k] = neg[bu * KNEG + k];

    // ---- per-half word table, all indices compile-time (rule #20) ----
    int words[8];
#pragma unroll
    for (int jj = 0; jj < 8; ++jj) {
        // half 0 slot: j = jj (always a ctx slot); mask to negw[0] if j>=len
        const int w0 = (jj < len) ? ctxw[jj] : negw[0];
        // half 1 slot: j = 8+jj
        int w1;
        if (jj < 2)       w1 = ((8 + jj) < len) ? ctxw[8 + jj] : negw[0];
        else if (jj < 7)  w1 = negw[jj - 2];     // j = 10..14
        else              w1 = negw[0];          // j = 15 dummy
        words[jj] = half ? w1 : w0;
    }

    // Drain vmem (only the out[] zero-store can be outstanding here; index
    // loads are SMEM) so vmcnt counts exactly our 9 gathers.
    asm volatile("s_waitcnt vmcnt(0)" ::: "memory");

    // ---- issue all 9 row gathers back-to-back ----
    const uint32_t sub16 = (uint32_t)sub * 16u;
    f32x4 tv;
    {
        uint32_t off = (uint32_t)t_word * (DIM * 4u) + sub16;
        asm volatile("global_load_dwordx4 %0, %1, %2"
                     : "=v"(tv) : "v"(off), "s"(in_emb));
    }
    f32x4 rv[8];
#pragma unroll
    for (int jj = 0; jj < 8; ++jj) {
        uint32_t off = (uint32_t)words[jj] * (DIM * 4u) + sub16;
        asm volatile("global_load_dwordx4 %0, %1, %2"
                     : "=v"(rv[jj]) : "v"(off), "s"(out_emb));
    }

    // ---- staged waits: consume load jj once tv and rv[0..jj] have landed ----
    float p[8];
#pragma unroll
    for (int jj = 0; jj < 8; ++jj) {
        asm volatile("s_waitcnt vmcnt(%[cnt])"
                     : "+v"(rv[jj]), "+v"(tv)
                     : [cnt] "i"(7 - jj)
                     : "memory");
        float d = tv.x * rv[jj].x + tv.y * rv[jj].y +
                  tv.z * rv[jj].z + tv.w * rv[jj].w;
        p[jj] = dpp_reduce32_to_lane31(d);   // valid on lanes 31 / 63
    }

    // ---- fused loss: broadcast 8 half-scores, 8 lanes per half do the math ----
    float bc[8];
#pragma unroll
    for (int jj = 0; jj < 8; ++jj) bc[jj] = __shfl(p[jj], 31, 32);

    const int sel = sub & 7;
    float a0 = (sel & 1) ? bc[1] : bc[0];
    float a1 = (sel & 1) ? bc[3] : bc[2];
    float a2 = (sel & 1) ? bc[5] : bc[4];
    float a3 = (sel & 1) ? bc[7] : bc[6];
    float b0 = (sel & 2) ? a1 : a0;
    float b1 = (sel & 2) ? a3 : a2;
    float s  = (sel & 4) ? b1 : b0;

    const int  j        = half * 8 + sel;
    const bool neg_slot = (j >= CMAX) && (j < CMAX + KNEG);
    const bool active   = (sub < 8);

    float v    = log_sigmoid(neg_slot ? -s : s);
    // j<len implies j<=9 (len<=CMAX), so pos/neg never overlap; j=15 dummy and
    // masked ctx slots (their s is the harmless t . neg0 score) fail both.
    float posc = (active && j < len)  ? v : 0.0f;
    float negc = (active && neg_slot) ? v : 0.0f;

    posc += __shfl_xor(posc, 1, 64);
    posc += __shfl_xor(posc, 2, 64);
    posc += __shfl_xor(posc, 4, 64);
    posc += __shfl_xor(posc, 32, 64);
    negc += __shfl_xor(negc, 1, 64);
    negc += __shfl_xor(negc, 2, 64);
    negc += __shfl_xor(negc, 4, 64);
    negc += __shfl_xor(negc, 32, 64);

    if (lane == 0) {
        float2 r;
        if (len > 0) {
            r.x = -posc / (float)len;
            r.y = -negc * (1.0f / KNEG);
        } else {
            r.x = 0.0f;
            r.y = 0.0f;
        }
        per_sample[b] = r;
    }
}

// ---------------------------------------------------------------------------
// Kernel B: one thread per sample, reads 128 KB of float2 from L2.
// ---------------------------------------------------------------------------
__global__ __launch_bounds__(256) void reduce_kernel(
    const float2* __restrict__ per_sample,
    float*        __restrict__ out)
{
    const int tid = threadIdx.x;
    const int b   = blockIdx.x * 256 + tid;   // 64 blocks cover BATCH exactly

    const float2 pr = per_sample[b];
    float pos = pr.x;
    float neg = pr.y;

#pragma unroll
    for (int m = 32; m >= 1; m >>= 1) {
        pos += __shfl_xor(pos, m, 64);
        neg += __shfl_xor(neg, m, 64);
    }
    __shared__ float s_pos[4];
    __shared__ float s_neg[4];
    const int wave = tid >> 6;
    if ((tid & 63) == 0) { s_pos[wave] = pos; s_neg[wave] = neg; }
    __syncthreads();
    if (tid == 0) {
        float ps = s_pos[0] + s_pos[1] + s_pos[2] + s_pos[3];
        float ns = s_neg[0] + s_neg[1] + s_neg[2] + s_neg[3];
        atomicAdd(&out[0], ps * (1.0f / BATCH));
        atomicAdd(&out[1], ns * (1.0f / BATCH));
    }
}

extern "C" void kernel_launch(void* const* d_in, const int* in_sizes, int n_in,
                              void* d_out, int out_size, void* d_ws, size_t ws_size,
                              hipStream_t stream) {
    const int*   tgt     = (const int*)  d_in[0];
    const int*   ctx     = (const int*)  d_in[1];
    const int*   lens    = (const int*)  d_in[2];
    const int*   neg     = (const int*)  d_in[3];
    const float* in_emb  = (const float*)d_in[4];
    const float* out_emb = (const float*)d_in[5];
    float* out          = (float*)d_out;
    float2* per_sample  = (float2*)d_ws;      // BATCH * 8 B = 128 KiB scratch

    // one 64-lane wave per sample; 4 samples per 256-thread block
    score_loss_kernel<<<BATCH / 4, 256, 0, stream>>>(
        tgt, ctx, lens, neg, in_emb, out_emb, per_sample, out);

    reduce_kernel<<<BATCH / 256, 256, 0, stream>>>(per_sample, out);
}